// Round 1
// baseline (671.038 us; speedup 1.0000x reference)
//
#include <hip/hip_runtime.h>

#define HID 64

// ---------------- degree / dinv ----------------
__global__ __launch_bounds__(256) void k_deg(const int* __restrict__ dst,
                                             const float* __restrict__ ew,
                                             float* deg, int nE) {
  int e = blockIdx.x * 256 + threadIdx.x;
  if (e < nE) unsafeAtomicAdd(&deg[dst[e]], ew[e]);
}

__global__ __launch_bounds__(256) void k_dinv(float* deg, int n) {
  int i = blockIdx.x * 256 + threadIdx.x;
  if (i < n) deg[i] = rsqrtf(deg[i] + 1.0f);  // +1 = self-loop weight
}

// ---------------- dense 64x64 projection: one node-row per thread ----------------
__global__ __launch_bounds__(256) void k_gemm64(const float* __restrict__ X,
                                                const float* __restrict__ W,
                                                float* __restrict__ Out, int n) {
  __shared__ float Ws[HID * HID];
  for (int idx = threadIdx.x; idx < HID * HID; idx += 256) Ws[idx] = W[idx];
  __syncthreads();
  int node = blockIdx.x * 256 + threadIdx.x;
  if (node >= n) return;
  const float4* xr = (const float4*)(X + (size_t)node * HID);
  float4 acc[16];
#pragma unroll
  for (int j = 0; j < 16; ++j) acc[j] = make_float4(0.f, 0.f, 0.f, 0.f);
#pragma unroll 4
  for (int k4 = 0; k4 < 16; ++k4) {
    float4 xv = xr[k4];
#pragma unroll
    for (int kk = 0; kk < 4; ++kk) {
      float xk = (kk == 0) ? xv.x : (kk == 1) ? xv.y : (kk == 2) ? xv.z : xv.w;
      const float4* wr = (const float4*)(Ws + (k4 * 4 + kk) * HID);
#pragma unroll
      for (int j = 0; j < 16; ++j) {
        float4 w = wr[j];
        acc[j].x = fmaf(xk, w.x, acc[j].x);
        acc[j].y = fmaf(xk, w.y, acc[j].y);
        acc[j].z = fmaf(xk, w.z, acc[j].z);
        acc[j].w = fmaf(xk, w.w, acc[j].w);
      }
    }
  }
  float4* orow = (float4*)(Out + (size_t)node * HID);
#pragma unroll
  for (int j = 0; j < 16; ++j) orow[j] = acc[j];
}

// ---------------- edge scatter: one wave per edge, lane j = channel j ----------------
__global__ __launch_bounds__(256) void k_scatter(const int* __restrict__ src,
                                                 const int* __restrict__ dst,
                                                 const float* __restrict__ ew,
                                                 const float* __restrict__ dinv,
                                                 const float* __restrict__ Hin,
                                                 float* agg, int nE) {
  int gid = blockIdx.x * 256 + threadIdx.x;
  int e = gid >> 6;
  int j = gid & 63;
  if (e >= nE) return;
  int s = src[e];
  int d = dst[e];
  float norm = dinv[s] * ew[e] * dinv[d];
  float v = Hin[(size_t)s * HID + j] * norm;
  unsafeAtomicAdd(&agg[(size_t)d * HID + j], v);
}

// ---------------- epilogue: agg + dinv^2 * h (self-loop) + bias, optional relu ----------------
__global__ __launch_bounds__(256) void k_epilogue(const float* agg,
                                                  const float* __restrict__ Hin,
                                                  const float* __restrict__ dinv,
                                                  const float* __restrict__ bias,
                                                  float* outp, int total, int do_relu) {
  int gid = blockIdx.x * 256 + threadIdx.x;
  if (gid >= total) return;
  int i = gid >> 6;
  int j = gid & 63;
  float di = dinv[i];
  float v = agg[gid] + di * di * Hin[gid] + bias[j];
  if (do_relu) v = fmaxf(v, 0.f);
  outp[gid] = v;
}

extern "C" void kernel_launch(void* const* d_in, const int* in_sizes, int n_in,
                              void* d_out, int out_size, void* d_ws, size_t ws_size,
                              hipStream_t stream) {
  const float* x  = (const float*)d_in[0];
  const int*   ei = (const int*)d_in[1];
  const float* ew = (const float*)d_in[2];
  const float* W1 = (const float*)d_in[3];
  const float* b1 = (const float*)d_in[4];
  const float* W2 = (const float*)d_in[5];
  const float* b2 = (const float*)d_in[6];
  float* out = (float*)d_out;

  const int n  = in_sizes[0] / HID;   // 100000
  const int nE = in_sizes[2];         // 1000000
  const int* src = ei;
  const int* dst = ei + nE;

  char* ws = (char*)d_ws;
  float* dinv = (float*)ws;                                   // n floats
  size_t off = (((size_t)n * 4) + 511) & ~(size_t)511;
  float* bufA = (float*)(ws + off);                           // n*64 floats
  float* bufB = (float*)(ws + off + (size_t)n * HID * 4);     // n*64 floats

  const size_t featBytes = (size_t)n * HID * 4;
  const int total = n * HID;

  // degrees (shared by both layers)
  hipMemsetAsync(dinv, 0, (size_t)n * 4, stream);
  k_deg<<<(nE + 255) / 256, 256, 0, stream>>>(dst, ew, dinv, nE);
  k_dinv<<<(n + 255) / 256, 256, 0, stream>>>(dinv, n);

  // ---- layer 1 ----
  k_gemm64<<<(n + 255) / 256, 256, 0, stream>>>(x, W1, bufA, n);
  hipMemsetAsync(bufB, 0, featBytes, stream);
  k_scatter<<<(nE * 64) / 256, 256, 0, stream>>>(src, dst, ew, dinv, bufA, bufB, nE);
  k_epilogue<<<(total + 255) / 256, 256, 0, stream>>>(bufB, bufA, dinv, b1, bufB, total, 1);

  // ---- layer 2 ----
  k_gemm64<<<(n + 255) / 256, 256, 0, stream>>>(bufB, W2, bufA, n);
  hipMemsetAsync(out, 0, featBytes, stream);
  k_scatter<<<(nE * 64) / 256, 256, 0, stream>>>(src, dst, ew, dinv, bufA, out, nE);
  k_epilogue<<<(total + 255) / 256, 256, 0, stream>>>(out, bufA, dinv, b2, out, total, 0);
}

// Round 2
// 500.125 us; speedup vs baseline: 1.3417x; 1.3417x over previous
//
#include <hip/hip_runtime.h>

#define HID 64

__device__ inline float readlane_f(float v, int l) {
  return __int_as_float(__builtin_amdgcn_readlane(__float_as_int(v), l));
}

// ---- per-edge: int degree count + weighted degree ----
__global__ __launch_bounds__(256) void k_count(const int* __restrict__ dst,
                                               const float* __restrict__ ew,
                                               int* __restrict__ cnt,
                                               float* __restrict__ degw, int nE) {
  int e = blockIdx.x * 256 + threadIdx.x;
  if (e >= nE) return;
  int d = dst[e];
  atomicAdd(&cnt[d], 1);
  unsafeAtomicAdd(&degw[d], ew[e]);
}

// ---- block-local exclusive scan of counts ----
__global__ __launch_bounds__(256) void k_scan1(const int* __restrict__ cnt,
                                               int* __restrict__ rowStart,
                                               int* __restrict__ blockSums, int n) {
  __shared__ int s[256];
  int i = blockIdx.x * 256 + threadIdx.x;
  int v = (i < n) ? cnt[i] : 0;
  s[threadIdx.x] = v;
  __syncthreads();
  for (int off = 1; off < 256; off <<= 1) {
    int t = (threadIdx.x >= (unsigned)off) ? s[threadIdx.x - off] : 0;
    __syncthreads();
    s[threadIdx.x] += t;
    __syncthreads();
  }
  if (i < n) rowStart[i] = s[threadIdx.x] - v;  // exclusive
  if (threadIdx.x == 255) blockSums[blockIdx.x] = s[255];
}

// ---- scan the block sums (nb <= 512) ----
__global__ __launch_bounds__(512) void k_scan2(int* blockSums, int nb) {
  __shared__ int s[512];
  int v = (threadIdx.x < (unsigned)nb) ? blockSums[threadIdx.x] : 0;
  s[threadIdx.x] = v;
  __syncthreads();
  for (int off = 1; off < 512; off <<= 1) {
    int t = (threadIdx.x >= (unsigned)off) ? s[threadIdx.x - off] : 0;
    __syncthreads();
    s[threadIdx.x] += t;
    __syncthreads();
  }
  if (threadIdx.x < (unsigned)nb) blockSums[threadIdx.x] = s[threadIdx.x] - v;
}

__global__ __launch_bounds__(256) void k_scan3(int* rowStart, const int* __restrict__ blockSums,
                                               int n, int nE) {
  int i = blockIdx.x * 256 + threadIdx.x;
  if (i < n) rowStart[i] += blockSums[blockIdx.x];
  if (i == 0) rowStart[n] = nE;
}

__global__ __launch_bounds__(256) void k_dinv(float* degw, int n) {
  int i = blockIdx.x * 256 + threadIdx.x;
  if (i < n) degw[i] = rsqrtf(degw[i] + 1.0f);  // +1 = self-loop
}

// ---- fill CSR with {src, norm} records ----
__global__ __launch_bounds__(256) void k_fill(const int* __restrict__ src,
                                              const int* __restrict__ dst,
                                              const float* __restrict__ ew,
                                              const float* __restrict__ dinv,
                                              const int* __restrict__ rowStart,
                                              int* cursor, int2* __restrict__ edges, int nE) {
  int e = blockIdx.x * 256 + threadIdx.x;
  if (e >= nE) return;
  int s = src[e], d = dst[e];
  float norm = dinv[s] * ew[e] * dinv[d];
  int pos = rowStart[d] + atomicAdd(&cursor[d], 1);
  edges[pos] = make_int2(s, __float_as_int(norm));
}

// ---- dense 64x64 projection: lane j holds W column j; readlane-broadcast x ----
__global__ __launch_bounds__(256) void k_gemm64(const float* __restrict__ X,
                                                const float* __restrict__ W,
                                                float* __restrict__ Out, int n) {
  int lane = threadIdx.x & 63;
  float Wc[HID];
#pragma unroll
  for (int k = 0; k < HID; ++k) Wc[k] = W[k * HID + lane];
  int wave = (blockIdx.x * 256 + threadIdx.x) >> 6;
  int nwaves = (gridDim.x * 256) >> 6;
  for (int node = wave; node < n; node += nwaves) {
    float xl = X[(size_t)node * HID + lane];
    float acc = 0.f;
#pragma unroll
    for (int k = 0; k < HID; ++k) acc = fmaf(readlane_f(xl, k), Wc[k], acc);
    Out[(size_t)node * HID + lane] = acc;
  }
}

// ---- CSR aggregate: one wave per node, lane=channel; fused self-loop+bias+relu ----
__global__ __launch_bounds__(256) void k_aggregate(const int2* __restrict__ edges,
                                                   const int* __restrict__ rowStart,
                                                   const float* __restrict__ dinv,
                                                   const float* __restrict__ Hin,
                                                   const float* __restrict__ bias,
                                                   float* __restrict__ outp, int n, int do_relu) {
  int gid = blockIdx.x * 256 + threadIdx.x;
  int node = gid >> 6;
  int j = gid & 63;
  if (node >= n) return;
  float di = dinv[node];
  float acc = di * di * Hin[(size_t)node * HID + j];
  int e0 = rowStart[node];
  int e1 = rowStart[node + 1];
  for (int e = e0; e < e1; ++e) {
    int2 r = edges[e];
    acc = fmaf(__int_as_float(r.y), Hin[(size_t)r.x * HID + j], acc);
  }
  acc += bias[j];
  if (do_relu) acc = fmaxf(acc, 0.f);
  outp[(size_t)node * HID + j] = acc;
}

extern "C" void kernel_launch(void* const* d_in, const int* in_sizes, int n_in,
                              void* d_out, int out_size, void* d_ws, size_t ws_size,
                              hipStream_t stream) {
  const float* x  = (const float*)d_in[0];
  const int*   ei = (const int*)d_in[1];
  const float* ew = (const float*)d_in[2];
  const float* W1 = (const float*)d_in[3];
  const float* b1 = (const float*)d_in[4];
  const float* W2 = (const float*)d_in[5];
  const float* b2 = (const float*)d_in[6];
  float* out = (float*)d_out;

  const int n  = in_sizes[0] / HID;   // 100000
  const int nE = in_sizes[2];         // 1000000
  const int* src = ei;
  const int* dst = ei + nE;

  auto align512 = [](size_t v) { return (v + 511) & ~(size_t)511; };
  char* ws = (char*)d_ws;
  size_t off = 0;
  float* dinv     = (float*)(ws + off); off += align512((size_t)n * 4);
  int*   cnt      = (int*)  (ws + off); off += align512((size_t)n * 4);
  int*   rowStart = (int*)  (ws + off); off += align512((size_t)(n + 1) * 4);
  int*   blockSums= (int*)  (ws + off); off += align512(512 * 4);
  int2*  edges    = (int2*) (ws + off); off += align512((size_t)nE * 8);
  float* bufA     = (float*)(ws + off); off += align512((size_t)n * HID * 4);
  float* bufB     = (float*)(ws + off);

  const int nbScan = (n + 255) / 256;          // 391
  const int edgeBlocks = (nE + 255) / 256;
  const int featBlocks = (n * HID + 255) / 256; // wave-per-node aggregate grid

  // ---- CSR build (shared by both layers) ----
  hipMemsetAsync(dinv, 0, (size_t)n * 4, stream);
  hipMemsetAsync(cnt, 0, (size_t)n * 4, stream);
  k_count<<<edgeBlocks, 256, 0, stream>>>(dst, ew, cnt, dinv, nE);
  k_scan1<<<nbScan, 256, 0, stream>>>(cnt, rowStart, blockSums, n);
  k_scan2<<<1, 512, 0, stream>>>(blockSums, nbScan);
  k_scan3<<<nbScan, 256, 0, stream>>>(rowStart, blockSums, n, nE);
  k_dinv<<<nbScan, 256, 0, stream>>>(dinv, n);
  hipMemsetAsync(cnt, 0, (size_t)n * 4, stream);  // reuse as cursor
  k_fill<<<edgeBlocks, 256, 0, stream>>>(src, dst, ew, dinv, rowStart, cnt, edges, nE);

  // ---- layer 1 ----
  k_gemm64<<<2048, 256, 0, stream>>>(x, W1, bufA, n);
  k_aggregate<<<featBlocks, 256, 0, stream>>>(edges, rowStart, dinv, bufA, b1, bufB, n, 1);

  // ---- layer 2 ----
  k_gemm64<<<2048, 256, 0, stream>>>(bufB, W2, bufA, n);
  k_aggregate<<<featBlocks, 256, 0, stream>>>(edges, rowStart, dinv, bufA, b2, out, n, 0);
}

// Round 3
// 376.104 us; speedup vs baseline: 1.7842x; 1.3298x over previous
//
#include <hip/hip_runtime.h>

#define HID 64

__device__ inline float readlane_f(float v, int l) {
  return __int_as_float(__builtin_amdgcn_readlane(__float_as_int(v), l));
}

// ---- per-edge: int degree count + weighted degree ----
__global__ __launch_bounds__(256) void k_count(const int* __restrict__ dst,
                                               const float* __restrict__ ew,
                                               int* __restrict__ cnt,
                                               float* __restrict__ degw, int nE) {
  int e = blockIdx.x * 256 + threadIdx.x;
  if (e >= nE) return;
  int d = dst[e];
  atomicAdd(&cnt[d], 1);
  unsafeAtomicAdd(&degw[d], ew[e]);
}

// ---- block-local exclusive scan of counts ----
__global__ __launch_bounds__(256) void k_scan1(const int* __restrict__ cnt,
                                               int* __restrict__ rowStart,
                                               int* __restrict__ blockSums, int n) {
  __shared__ int s[256];
  int i = blockIdx.x * 256 + threadIdx.x;
  int v = (i < n) ? cnt[i] : 0;
  s[threadIdx.x] = v;
  __syncthreads();
  for (int off = 1; off < 256; off <<= 1) {
    int t = (threadIdx.x >= (unsigned)off) ? s[threadIdx.x - off] : 0;
    __syncthreads();
    s[threadIdx.x] += t;
    __syncthreads();
  }
  if (i < n) rowStart[i] = s[threadIdx.x] - v;  // exclusive
  if (threadIdx.x == 255) blockSums[blockIdx.x] = s[255];
}

// ---- scan the block sums (nb <= 512) ----
__global__ __launch_bounds__(512) void k_scan2(int* blockSums, int nb) {
  __shared__ int s[512];
  int v = (threadIdx.x < (unsigned)nb) ? blockSums[threadIdx.x] : 0;
  s[threadIdx.x] = v;
  __syncthreads();
  for (int off = 1; off < 512; off <<= 1) {
    int t = (threadIdx.x >= (unsigned)off) ? s[threadIdx.x - off] : 0;
    __syncthreads();
    s[threadIdx.x] += t;
    __syncthreads();
  }
  if (threadIdx.x < (unsigned)nb) blockSums[threadIdx.x] = s[threadIdx.x] - v;
}

// ---- apply block offsets + compute dinv (fused) ----
__global__ __launch_bounds__(256) void k_scan3(int* rowStart, const int* __restrict__ blockSums,
                                               float* degw, int n, int nE) {
  int i = blockIdx.x * 256 + threadIdx.x;
  if (i < n) {
    rowStart[i] += blockSums[blockIdx.x];
    degw[i] = rsqrtf(degw[i] + 1.0f);  // +1 = self-loop weight
  }
  if (i == 0) rowStart[n] = nE;
}

// ---- fill CSR with {src, norm} records ----
__global__ __launch_bounds__(256) void k_fill(const int* __restrict__ src,
                                              const int* __restrict__ dst,
                                              const float* __restrict__ ew,
                                              const float* __restrict__ dinv,
                                              const int* __restrict__ rowStart,
                                              int* cursor, int2* __restrict__ edges, int nE) {
  int e = blockIdx.x * 256 + threadIdx.x;
  if (e >= nE) return;
  int s = src[e], d = dst[e];
  float norm = dinv[s] * ew[e] * dinv[d];
  int pos = rowStart[d] + atomicAdd(&cursor[d], 1);
  edges[pos] = make_int2(s, __float_as_int(norm));
}

// ---- dense 64x64 projection: lane j holds W column j; readlane-broadcast x ----
__global__ __launch_bounds__(256) void k_gemm64(const float* __restrict__ X,
                                                const float* __restrict__ W,
                                                float* __restrict__ Out, int n) {
  int lane = threadIdx.x & 63;
  float Wc[HID];
#pragma unroll
  for (int k = 0; k < HID; ++k) Wc[k] = W[k * HID + lane];
  int wave = (blockIdx.x * 256 + threadIdx.x) >> 6;
  int nwaves = (gridDim.x * 256) >> 6;
  for (int node = wave; node < n; node += nwaves) {
    float xl = X[(size_t)node * HID + lane];
    float acc = 0.f;
#pragma unroll
    for (int k = 0; k < HID; ++k) acc = fmaf(readlane_f(xl, k), Wc[k], acc);
    Out[(size_t)node * HID + lane] = acc;
  }
}

// ---- CSR aggregate: one wave per node, lane=channel; unroll-4 MLP; scalarized row ----
__global__ __launch_bounds__(256) void k_aggregate(const int2* __restrict__ edges,
                                                   const int* __restrict__ rowStart,
                                                   const float* __restrict__ dinv,
                                                   const float* __restrict__ Hin,
                                                   const float* __restrict__ bias,
                                                   float* __restrict__ outp, int n, int do_relu) {
  int j = threadIdx.x & 63;
  // node is wave-uniform; readfirstlane lets the compiler keep row state in SGPRs
  int node = __builtin_amdgcn_readfirstlane((blockIdx.x * 256 + threadIdx.x) >> 6);
  if (node >= n) return;
  int e0 = rowStart[node];
  int e1 = rowStart[node + 1];
  float di = dinv[node];
  float a0 = di * di * Hin[(size_t)node * HID + j];
  float a1 = 0.f, a2 = 0.f, a3 = 0.f;
  for (int e = e0; e < e1; e += 4) {
    int last = e1 - 1;
    int i1 = (e + 1 < e1) ? e + 1 : last;  // clamp tail: keeps 4 gathers in flight
    int i2 = (e + 2 < e1) ? e + 2 : last;
    int i3 = (e + 3 < e1) ? e + 3 : last;
    int2 r0 = edges[e];
    int2 r1 = edges[i1];
    int2 r2 = edges[i2];
    int2 r3 = edges[i3];
    float h0 = Hin[(size_t)r0.x * HID + j];
    float h1 = Hin[(size_t)r1.x * HID + j];
    float h2 = Hin[(size_t)r2.x * HID + j];
    float h3 = Hin[(size_t)r3.x * HID + j];
    float n0 = __int_as_float(r0.y);
    float n1 = (e + 1 < e1) ? __int_as_float(r1.y) : 0.f;
    float n2 = (e + 2 < e1) ? __int_as_float(r2.y) : 0.f;
    float n3 = (e + 3 < e1) ? __int_as_float(r3.y) : 0.f;
    a0 = fmaf(n0, h0, a0);
    a1 = fmaf(n1, h1, a1);
    a2 = fmaf(n2, h2, a2);
    a3 = fmaf(n3, h3, a3);
  }
  float acc = ((a0 + a1) + (a2 + a3)) + bias[j];
  if (do_relu) acc = fmaxf(acc, 0.f);
  outp[(size_t)node * HID + j] = acc;
}

extern "C" void kernel_launch(void* const* d_in, const int* in_sizes, int n_in,
                              void* d_out, int out_size, void* d_ws, size_t ws_size,
                              hipStream_t stream) {
  const float* x  = (const float*)d_in[0];
  const int*   ei = (const int*)d_in[1];
  const float* ew = (const float*)d_in[2];
  const float* W1 = (const float*)d_in[3];
  const float* b1 = (const float*)d_in[4];
  const float* W2 = (const float*)d_in[5];
  const float* b2 = (const float*)d_in[6];
  float* out = (float*)d_out;

  const int n  = in_sizes[0] / HID;   // 100000
  const int nE = in_sizes[2];         // 1000000
  const int* src = ei;
  const int* dst = ei + nE;

  auto align512 = [](size_t v) { return (v + 511) & ~(size_t)511; };
  char* ws = (char*)d_ws;
  size_t off = 0;
  float* dinv     = (float*)(ws + off); off += align512((size_t)n * 4);
  int*   cnt      = (int*)  (ws + off); off += align512((size_t)n * 4);
  int*   rowStart = (int*)  (ws + off); off += align512((size_t)(n + 1) * 4);
  int*   blockSums= (int*)  (ws + off); off += align512(512 * 4);
  int2*  edges    = (int2*) (ws + off); off += align512((size_t)nE * 8);
  float* bufA     = (float*)(ws + off); off += align512((size_t)n * HID * 4);
  float* bufB     = (float*)(ws + off);

  const int nbScan = (n + 255) / 256;          // 391
  const int edgeBlocks = (nE + 255) / 256;
  const int featBlocks = (n * HID + 255) / 256; // wave-per-node aggregate grid

  // ---- CSR build (shared by both layers) ----
  // dinv and cnt are adjacent: one memset covers both
  hipMemsetAsync(dinv, 0, 2 * align512((size_t)n * 4), stream);
  k_count<<<edgeBlocks, 256, 0, stream>>>(dst, ew, cnt, dinv, nE);
  k_scan1<<<nbScan, 256, 0, stream>>>(cnt, rowStart, blockSums, n);
  k_scan2<<<1, 512, 0, stream>>>(blockSums, nbScan);
  k_scan3<<<nbScan, 256, 0, stream>>>(rowStart, blockSums, dinv, n, nE);
  hipMemsetAsync(cnt, 0, (size_t)n * 4, stream);  // reuse as cursor
  k_fill<<<edgeBlocks, 256, 0, stream>>>(src, dst, ew, dinv, rowStart, cnt, edges, nE);

  // ---- layer 1 ----
  k_gemm64<<<2048, 256, 0, stream>>>(x, W1, bufA, n);
  k_aggregate<<<featBlocks, 256, 0, stream>>>(edges, rowStart, dinv, bufA, b1, bufB, n, 1);

  // ---- layer 2 ----
  k_gemm64<<<2048, 256, 0, stream>>>(bufB, W2, bufA, n);
  k_aggregate<<<featBlocks, 256, 0, stream>>>(edges, rowStart, dinv, bufA, b2, out, n, 0);
}

// Round 4
// 302.072 us; speedup vs baseline: 2.2215x; 1.2451x over previous
//
#include <hip/hip_runtime.h>

#define HID 64
#define FXS 1048576.0f   // 2^20 fixed-point scale for edge weights

// ---- count: 8-way privatized packed 64-bit atomic; returns per-(copy,dst) rank ----
// P[c][d] accumulates (count << 40) | sum(fixed20(ew)); rank = count before this edge.
__global__ __launch_bounds__(256) void k_count(const int* __restrict__ dst,
                                               const float* __restrict__ ew,
                                               unsigned long long* P,
                                               int* __restrict__ rank, int n, int nE) {
  int e = blockIdx.x * 256 + threadIdx.x;
  if (e >= nE) return;
  int d = dst[e];
  unsigned int fx = __float2uint_rn(ew[e] * FXS);
  int c = (e >> 8) & 7;  // == blockIdx & 7
  unsigned long long old =
      atomicAdd(&P[(size_t)c * n + d], (1ull << 40) | (unsigned long long)fx);
  rank[e] = (int)(old >> 40);
}

// ---- scan1: reduce 8 copies -> total count + weighted degree; per-copy excl offsets
// stored back into P in place; block-local exclusive scan of totals ----
__global__ __launch_bounds__(256) void k_scan1(unsigned long long* P,
                                               float* __restrict__ degw,
                                               int* __restrict__ rowStart,
                                               int* __restrict__ blockSums, int n) {
  __shared__ int s[256];
  int i = blockIdx.x * 256 + threadIdx.x;
  int t = 0;
  if (i < n) {
    const unsigned long long mask = (1ull << 40) - 1;
    int off = 0;
    float dw = 0.f;
#pragma unroll
    for (int c = 0; c < 8; ++c) {
      unsigned long long p = P[(size_t)c * n + i];
      int cc = (int)(p >> 40);
      dw += (float)(p & mask);
      P[(size_t)c * n + i] = (unsigned long long)(unsigned)off;  // per-copy excl offset
      off += cc;
    }
    degw[i] = dw * (1.f / FXS);
    t = off;
  }
  s[threadIdx.x] = t;
  __syncthreads();
  for (int o = 1; o < 256; o <<= 1) {
    int tv = (threadIdx.x >= (unsigned)o) ? s[threadIdx.x - o] : 0;
    __syncthreads();
    s[threadIdx.x] += tv;
    __syncthreads();
  }
  if (i < n) rowStart[i] = s[threadIdx.x] - t;  // exclusive
  if (threadIdx.x == 255) blockSums[blockIdx.x] = s[255];
}

// ---- scan the block sums (nb <= 512) ----
__global__ __launch_bounds__(512) void k_scan2(int* blockSums, int nb) {
  __shared__ int s[512];
  int v = (threadIdx.x < (unsigned)nb) ? blockSums[threadIdx.x] : 0;
  s[threadIdx.x] = v;
  __syncthreads();
  for (int off = 1; off < 512; off <<= 1) {
    int t = (threadIdx.x >= (unsigned)off) ? s[threadIdx.x - off] : 0;
    __syncthreads();
    s[threadIdx.x] += t;
    __syncthreads();
  }
  if (threadIdx.x < (unsigned)nb) blockSums[threadIdx.x] = s[threadIdx.x] - v;
}

// ---- apply block offsets + compute dinv (fused) ----
__global__ __launch_bounds__(256) void k_scan3(int* rowStart, const int* __restrict__ blockSums,
                                               float* degw, int n, int nE) {
  int i = blockIdx.x * 256 + threadIdx.x;
  if (i < n) {
    rowStart[i] += blockSums[blockIdx.x];
    degw[i] = rsqrtf(degw[i] + 1.0f);  // +1 = self-loop weight
  }
  if (i == 0) rowStart[n] = nE;
}

// ---- fill CSR: NO atomics; pos = rowStart + copyOff + rank ----
__global__ __launch_bounds__(256) void k_fill(const int* __restrict__ src,
                                              const int* __restrict__ dst,
                                              const float* __restrict__ ew,
                                              const float* __restrict__ dinv,
                                              const int* __restrict__ rowStart,
                                              const unsigned long long* __restrict__ P,
                                              const int* __restrict__ rank,
                                              int2* __restrict__ edges, int n, int nE) {
  int e = blockIdx.x * 256 + threadIdx.x;
  if (e >= nE) return;
  int s = src[e], d = dst[e];
  int c = (e >> 8) & 7;
  float norm = dinv[s] * ew[e] * dinv[d];
  int pos = rowStart[d] + (int)P[(size_t)c * n + d] + rank[e];
  edges[pos] = make_int2(s, __float_as_int(norm));
}

// ---- dense 64x64 projection: lane j holds W column j; readlane-broadcast x ----
__device__ inline float readlane_f(float v, int l) {
  return __int_as_float(__builtin_amdgcn_readlane(__float_as_int(v), l));
}

__global__ __launch_bounds__(256) void k_gemm64(const float* __restrict__ X,
                                                const float* __restrict__ W,
                                                float* __restrict__ Out, int n) {
  int lane = threadIdx.x & 63;
  float Wc[HID];
#pragma unroll
  for (int k = 0; k < HID; ++k) Wc[k] = W[k * HID + lane];
  int wave = (blockIdx.x * 256 + threadIdx.x) >> 6;
  int nwaves = (gridDim.x * 256) >> 6;
  for (int node = wave; node < n; node += nwaves) {
    float xl = X[(size_t)node * HID + lane];
    float a0 = 0.f, a1 = 0.f;  // 2 accs break the 64-deep fma chain
#pragma unroll
    for (int k = 0; k < HID; k += 2) {
      a0 = fmaf(readlane_f(xl, k), Wc[k], a0);
      a1 = fmaf(readlane_f(xl, k + 1), Wc[k + 1], a1);
    }
    Out[(size_t)node * HID + lane] = a0 + a1;
  }
}

// ---- CSR aggregate: one wave per node, lane=channel; unroll-8 MLP; scalarized row ----
__global__ __launch_bounds__(256) void k_aggregate(const int2* __restrict__ edges,
                                                   const int* __restrict__ rowStart,
                                                   const float* __restrict__ dinv,
                                                   const float* __restrict__ Hin,
                                                   const float* __restrict__ bias,
                                                   float* __restrict__ outp, int n, int do_relu) {
  int j = threadIdx.x & 63;
  int node = __builtin_amdgcn_readfirstlane((blockIdx.x * 256 + threadIdx.x) >> 6);
  if (node >= n) return;
  int e0 = rowStart[node];
  int e1 = rowStart[node + 1];
  float di = dinv[node];
  float a0 = di * di * Hin[(size_t)node * HID + j];
  float a1 = 0.f, a2 = 0.f, a3 = 0.f, a4 = 0.f, a5 = 0.f, a6 = 0.f, a7 = 0.f;
  for (int e = e0; e < e1; e += 8) {
    int last = e1 - 1;
    int i1 = (e + 1 < e1) ? e + 1 : last;  // clamp tail: keep 8 gathers in flight
    int i2 = (e + 2 < e1) ? e + 2 : last;
    int i3 = (e + 3 < e1) ? e + 3 : last;
    int i4 = (e + 4 < e1) ? e + 4 : last;
    int i5 = (e + 5 < e1) ? e + 5 : last;
    int i6 = (e + 6 < e1) ? e + 6 : last;
    int i7 = (e + 7 < e1) ? e + 7 : last;
    int2 r0 = edges[e];
    int2 r1 = edges[i1];
    int2 r2 = edges[i2];
    int2 r3 = edges[i3];
    int2 r4 = edges[i4];
    int2 r5 = edges[i5];
    int2 r6 = edges[i6];
    int2 r7 = edges[i7];
    float h0 = Hin[(size_t)r0.x * HID + j];
    float h1 = Hin[(size_t)r1.x * HID + j];
    float h2 = Hin[(size_t)r2.x * HID + j];
    float h3 = Hin[(size_t)r3.x * HID + j];
    float h4 = Hin[(size_t)r4.x * HID + j];
    float h5 = Hin[(size_t)r5.x * HID + j];
    float h6 = Hin[(size_t)r6.x * HID + j];
    float h7 = Hin[(size_t)r7.x * HID + j];
    float n0 = __int_as_float(r0.y);
    float n1 = (e + 1 < e1) ? __int_as_float(r1.y) : 0.f;
    float n2 = (e + 2 < e1) ? __int_as_float(r2.y) : 0.f;
    float n3 = (e + 3 < e1) ? __int_as_float(r3.y) : 0.f;
    float n4 = (e + 4 < e1) ? __int_as_float(r4.y) : 0.f;
    float n5 = (e + 5 < e1) ? __int_as_float(r5.y) : 0.f;
    float n6 = (e + 6 < e1) ? __int_as_float(r6.y) : 0.f;
    float n7 = (e + 7 < e1) ? __int_as_float(r7.y) : 0.f;
    a0 = fmaf(n0, h0, a0);
    a1 = fmaf(n1, h1, a1);
    a2 = fmaf(n2, h2, a2);
    a3 = fmaf(n3, h3, a3);
    a4 = fmaf(n4, h4, a4);
    a5 = fmaf(n5, h5, a5);
    a6 = fmaf(n6, h6, a6);
    a7 = fmaf(n7, h7, a7);
  }
  float acc = (((a0 + a1) + (a2 + a3)) + ((a4 + a5) + (a6 + a7))) + bias[j];
  if (do_relu) acc = fmaxf(acc, 0.f);
  outp[(size_t)node * HID + j] = acc;
}

extern "C" void kernel_launch(void* const* d_in, const int* in_sizes, int n_in,
                              void* d_out, int out_size, void* d_ws, size_t ws_size,
                              hipStream_t stream) {
  const float* x  = (const float*)d_in[0];
  const int*   ei = (const int*)d_in[1];
  const float* ew = (const float*)d_in[2];
  const float* W1 = (const float*)d_in[3];
  const float* b1 = (const float*)d_in[4];
  const float* W2 = (const float*)d_in[5];
  const float* b2 = (const float*)d_in[6];
  float* out = (float*)d_out;

  const int n  = in_sizes[0] / HID;   // 100000
  const int nE = in_sizes[2];         // 1000000
  const int* src = ei;
  const int* dst = ei + nE;

  auto align512 = [](size_t v) { return (v + 511) & ~(size_t)511; };
  char* ws = (char*)d_ws;
  size_t off = 0;
  float* dinv     = (float*)(ws + off); off += align512((size_t)n * 4);
  int*   rowStart = (int*)  (ws + off); off += align512((size_t)(n + 1) * 4);
  int*   blockSums= (int*)  (ws + off); off += align512(512 * 4);
  int2*  edges    = (int2*) (ws + off); off += align512((size_t)nE * 8);
  float* bufA     = (float*)(ws + off); off += align512((size_t)n * HID * 4);
  float* bufB     = (float*)(ws + off);

  // rank (4 MB) and P (6.4 MB) alias onto bufA: both are dead before gemm1 writes bufA
  int* rank = (int*)bufA;
  unsigned long long* P =
      (unsigned long long*)((char*)bufA + align512((size_t)nE * 4));

  const int nbScan = (n + 255) / 256;           // 391
  const int edgeBlocks = (nE + 255) / 256;
  const int featBlocks = (n * HID + 255) / 256; // wave-per-node aggregate grid

  // ---- CSR build (shared by both layers) ----
  hipMemsetAsync(P, 0, (size_t)8 * n * 8, stream);
  k_count<<<edgeBlocks, 256, 0, stream>>>(dst, ew, P, rank, n, nE);
  k_scan1<<<nbScan, 256, 0, stream>>>(P, dinv, rowStart, blockSums, n);
  k_scan2<<<1, 512, 0, stream>>>(blockSums, nbScan);
  k_scan3<<<nbScan, 256, 0, stream>>>(rowStart, blockSums, dinv, n, nE);
  k_fill<<<edgeBlocks, 256, 0, stream>>>(src, dst, ew, dinv, rowStart, P, rank, edges, nE ? n : n, nE);

  // ---- layer 1 ----
  k_gemm64<<<2048, 256, 0, stream>>>(x, W1, bufA, n);
  k_aggregate<<<featBlocks, 256, 0, stream>>>(edges, rowStart, dinv, bufA, b1, bufB, n, 1);

  // ---- layer 2 ----
  k_gemm64<<<2048, 256, 0, stream>>>(bufB, W2, bufA, n);
  k_aggregate<<<featBlocks, 256, 0, stream>>>(edges, rowStart, dinv, bufA, b2, out, n, 0);
}

// Round 5
// 297.172 us; speedup vs baseline: 2.2581x; 1.0165x over previous
//
#include <hip/hip_runtime.h>

#define HID 64
#define FXS 1048576.0f   // 2^20 fixed-point scale for edge weights

__device__ inline float bf2f(unsigned short u) {
  return __uint_as_float((unsigned int)u << 16);
}
__device__ inline unsigned short f2bf(float f) {
  unsigned int u = __float_as_uint(f);
  u += 0x7fff + ((u >> 16) & 1);  // round-to-nearest-even
  return (unsigned short)(u >> 16);
}

// ---- count: 8-way privatized packed 64-bit atomic; returns per-(copy,dst) rank ----
// P[c][d] accumulates (count << 40) | sum(fixed20(ew)); rank = count before this edge.
// NOTE: sits on the measured ~20 line-RMW/ns device atomic ceiling (R1/R3/R4 invariant).
__global__ __launch_bounds__(256) void k_count(const int* __restrict__ dst,
                                               const float* __restrict__ ew,
                                               unsigned long long* P,
                                               int* __restrict__ rank, int n, int nE) {
  int e = blockIdx.x * 256 + threadIdx.x;
  if (e >= nE) return;
  int d = dst[e];
  unsigned int fx = __float2uint_rn(ew[e] * FXS);
  int c = (e >> 8) & 7;  // == blockIdx & 7
  unsigned long long old =
      atomicAdd(&P[(size_t)c * n + d], (1ull << 40) | (unsigned long long)fx);
  rank[e] = (int)(old >> 40);
}

// ---- scan1: reduce 8 copies -> weighted degree; per-copy excl offsets in place;
// block-local exclusive scan of total counts ----
__global__ __launch_bounds__(256) void k_scan1(unsigned long long* P,
                                               float* __restrict__ degw,
                                               int* __restrict__ rowStart,
                                               int* __restrict__ blockSums, int n) {
  __shared__ int s[256];
  int i = blockIdx.x * 256 + threadIdx.x;
  int t = 0;
  if (i < n) {
    const unsigned long long mask = (1ull << 40) - 1;
    int off = 0;
    float dw = 0.f;
#pragma unroll
    for (int c = 0; c < 8; ++c) {
      unsigned long long p = P[(size_t)c * n + i];
      int cc = (int)(p >> 40);
      dw += (float)(p & mask);
      P[(size_t)c * n + i] = (unsigned long long)(unsigned)off;  // per-copy excl offset
      off += cc;
    }
    degw[i] = dw * (1.f / FXS);
    t = off;
  }
  s[threadIdx.x] = t;
  __syncthreads();
  for (int o = 1; o < 256; o <<= 1) {
    int tv = (threadIdx.x >= (unsigned)o) ? s[threadIdx.x - o] : 0;
    __syncthreads();
    s[threadIdx.x] += tv;
    __syncthreads();
  }
  if (i < n) rowStart[i] = s[threadIdx.x] - t;  // exclusive
  if (threadIdx.x == 255) blockSums[blockIdx.x] = s[255];
}

// ---- scan the block sums (nb <= 512) ----
__global__ __launch_bounds__(512) void k_scan2(int* blockSums, int nb) {
  __shared__ int s[512];
  int v = (threadIdx.x < (unsigned)nb) ? blockSums[threadIdx.x] : 0;
  s[threadIdx.x] = v;
  __syncthreads();
  for (int off = 1; off < 512; off <<= 1) {
    int t = (threadIdx.x >= (unsigned)off) ? s[threadIdx.x - off] : 0;
    __syncthreads();
    s[threadIdx.x] += t;
    __syncthreads();
  }
  if (threadIdx.x < (unsigned)nb) blockSums[threadIdx.x] = s[threadIdx.x] - v;
}

// ---- apply block offsets + compute dinv (fused) ----
__global__ __launch_bounds__(256) void k_scan3(int* rowStart, const int* __restrict__ blockSums,
                                               float* degw, int n, int nE) {
  int i = blockIdx.x * 256 + threadIdx.x;
  if (i < n) {
    rowStart[i] += blockSums[blockIdx.x];
    degw[i] = rsqrtf(degw[i] + 1.0f);  // +1 = self-loop weight
  }
  if (i == 0) rowStart[n] = nE;
}

// ---- fill CSR: NO atomics; pos = rowStart + copyOff + rank ----
__global__ __launch_bounds__(256) void k_fill(const int* __restrict__ src,
                                              const int* __restrict__ dst,
                                              const float* __restrict__ ew,
                                              const float* __restrict__ dinv,
                                              const int* __restrict__ rowStart,
                                              const unsigned long long* __restrict__ P,
                                              const int* __restrict__ rank,
                                              int2* __restrict__ edges, int n, int nE) {
  int e = blockIdx.x * 256 + threadIdx.x;
  if (e >= nE) return;
  int s = src[e], d = dst[e];
  int c = (e >> 8) & 7;
  float norm = dinv[s] * ew[e] * dinv[d];
  int pos = rowStart[d] + (int)P[(size_t)c * n + d] + rank[e];
  edges[pos] = make_int2(s, __float_as_int(norm));
}

// ---- dense 64x64 projection: lane j holds W column j; readlane-broadcast x ----
// Input templated (f32 for layer 1, bf16 for layer 2); output bf16.
__device__ inline float readlane_f(float v, int l) {
  return __int_as_float(__builtin_amdgcn_readlane(__float_as_int(v), l));
}

template <typename TI>
__global__ __launch_bounds__(256) void k_gemm64(const TI* __restrict__ X,
                                                const float* __restrict__ W,
                                                unsigned short* __restrict__ Out, int n) {
  int lane = threadIdx.x & 63;
  float Wc[HID];
#pragma unroll
  for (int k = 0; k < HID; ++k) Wc[k] = W[k * HID + lane];
  int wave = (blockIdx.x * 256 + threadIdx.x) >> 6;
  int nwaves = (gridDim.x * 256) >> 6;
  for (int node = wave; node < n; node += nwaves) {
    TI raw = X[(size_t)node * HID + lane];
    float xl;
    if (sizeof(TI) == 2) xl = bf2f((unsigned short)raw);
    else xl = (float)raw;
    float a0 = 0.f, a1 = 0.f;  // 2 accs break the 64-deep fma chain
#pragma unroll
    for (int k = 0; k < HID; k += 2) {
      a0 = fmaf(readlane_f(xl, k), Wc[k], a0);
      a1 = fmaf(readlane_f(xl, k + 1), Wc[k + 1], a1);
    }
    Out[(size_t)node * HID + lane] = f2bf(a0 + a1);
  }
}

// ---- CSR aggregate: one wave per node, lane=channel; unroll-8 MLP; bf16 gathers ----
// OUT_BF16=1 -> write bf16 (intermediate layer), else f32 (final output).
template <int OUT_BF16>
__global__ __launch_bounds__(256) void k_aggregate(const int2* __restrict__ edges,
                                                   const int* __restrict__ rowStart,
                                                   const float* __restrict__ dinv,
                                                   const unsigned short* __restrict__ Hin,
                                                   const float* __restrict__ bias,
                                                   void* __restrict__ outp, int n, int do_relu) {
  int j = threadIdx.x & 63;
  int node = __builtin_amdgcn_readfirstlane((blockIdx.x * 256 + threadIdx.x) >> 6);
  if (node >= n) return;
  int e0 = rowStart[node];
  int e1 = rowStart[node + 1];
  float di = dinv[node];
  float a0 = di * di * bf2f(Hin[(size_t)node * HID + j]);
  float a1 = 0.f, a2 = 0.f, a3 = 0.f, a4 = 0.f, a5 = 0.f, a6 = 0.f, a7 = 0.f;
  for (int e = e0; e < e1; e += 8) {
    int last = e1 - 1;
    int i1 = (e + 1 < e1) ? e + 1 : last;  // clamp tail: keep 8 gathers in flight
    int i2 = (e + 2 < e1) ? e + 2 : last;
    int i3 = (e + 3 < e1) ? e + 3 : last;
    int i4 = (e + 4 < e1) ? e + 4 : last;
    int i5 = (e + 5 < e1) ? e + 5 : last;
    int i6 = (e + 6 < e1) ? e + 6 : last;
    int i7 = (e + 7 < e1) ? e + 7 : last;
    int2 r0 = edges[e];
    int2 r1 = edges[i1];
    int2 r2 = edges[i2];
    int2 r3 = edges[i3];
    int2 r4 = edges[i4];
    int2 r5 = edges[i5];
    int2 r6 = edges[i6];
    int2 r7 = edges[i7];
    float h0 = bf2f(Hin[(size_t)r0.x * HID + j]);
    float h1 = bf2f(Hin[(size_t)r1.x * HID + j]);
    float h2 = bf2f(Hin[(size_t)r2.x * HID + j]);
    float h3 = bf2f(Hin[(size_t)r3.x * HID + j]);
    float h4 = bf2f(Hin[(size_t)r4.x * HID + j]);
    float h5 = bf2f(Hin[(size_t)r5.x * HID + j]);
    float h6 = bf2f(Hin[(size_t)r6.x * HID + j]);
    float h7 = bf2f(Hin[(size_t)r7.x * HID + j]);
    float n0 = __int_as_float(r0.y);
    float n1 = (e + 1 < e1) ? __int_as_float(r1.y) : 0.f;
    float n2 = (e + 2 < e1) ? __int_as_float(r2.y) : 0.f;
    float n3 = (e + 3 < e1) ? __int_as_float(r3.y) : 0.f;
    float n4 = (e + 4 < e1) ? __int_as_float(r4.y) : 0.f;
    float n5 = (e + 5 < e1) ? __int_as_float(r5.y) : 0.f;
    float n6 = (e + 6 < e1) ? __int_as_float(r6.y) : 0.f;
    float n7 = (e + 7 < e1) ? __int_as_float(r7.y) : 0.f;
    a0 = fmaf(n0, h0, a0);
    a1 = fmaf(n1, h1, a1);
    a2 = fmaf(n2, h2, a2);
    a3 = fmaf(n3, h3, a3);
    a4 = fmaf(n4, h4, a4);
    a5 = fmaf(n5, h5, a5);
    a6 = fmaf(n6, h6, a6);
    a7 = fmaf(n7, h7, a7);
  }
  float acc = (((a0 + a1) + (a2 + a3)) + ((a4 + a5) + (a6 + a7))) + bias[j];
  if (do_relu) acc = fmaxf(acc, 0.f);
  if (OUT_BF16)
    ((unsigned short*)outp)[(size_t)node * HID + j] = f2bf(acc);
  else
    ((float*)outp)[(size_t)node * HID + j] = acc;
}

extern "C" void kernel_launch(void* const* d_in, const int* in_sizes, int n_in,
                              void* d_out, int out_size, void* d_ws, size_t ws_size,
                              hipStream_t stream) {
  const float* x  = (const float*)d_in[0];
  const int*   ei = (const int*)d_in[1];
  const float* ew = (const float*)d_in[2];
  const float* W1 = (const float*)d_in[3];
  const float* b1 = (const float*)d_in[4];
  const float* W2 = (const float*)d_in[5];
  const float* b2 = (const float*)d_in[6];
  float* out = (float*)d_out;

  const int n  = in_sizes[0] / HID;   // 100000
  const int nE = in_sizes[2];         // 1000000
  const int* src = ei;
  const int* dst = ei + nE;

  auto align512 = [](size_t v) { return (v + 511) & ~(size_t)511; };
  char* ws = (char*)d_ws;
  size_t off = 0;
  float* dinv     = (float*)(ws + off); off += align512((size_t)n * 4);
  int*   rowStart = (int*)  (ws + off); off += align512((size_t)(n + 1) * 4);
  int*   blockSums= (int*)  (ws + off); off += align512(512 * 4);
  int2*  edges    = (int2*) (ws + off); off += align512((size_t)nE * 8);
  unsigned short* bufA = (unsigned short*)(ws + off); off += align512((size_t)n * HID * 2);
  unsigned short* bufB = (unsigned short*)(ws + off);

  // rank (4 MB) + P (6.4 MB) alias onto bufA (12.8 MB): dead before gemm1 writes bufA
  int* rank = (int*)bufA;
  unsigned long long* P =
      (unsigned long long*)((char*)bufA + align512((size_t)nE * 4));

  const int nbScan = (n + 255) / 256;           // 391
  const int edgeBlocks = (nE + 255) / 256;
  const int featBlocks = (n * HID + 255) / 256; // wave-per-node aggregate grid

  // ---- CSR build (shared by both layers) ----
  hipMemsetAsync(P, 0, (size_t)8 * n * 8, stream);
  k_count<<<edgeBlocks, 256, 0, stream>>>(dst, ew, P, rank, n, nE);
  k_scan1<<<nbScan, 256, 0, stream>>>(P, dinv, rowStart, blockSums, n);
  k_scan2<<<1, 512, 0, stream>>>(blockSums, nbScan);
  k_scan3<<<nbScan, 256, 0, stream>>>(rowStart, blockSums, dinv, n, nE);
  k_fill<<<edgeBlocks, 256, 0, stream>>>(src, dst, ew, dinv, rowStart, P, rank, edges, n, nE);

  // ---- layer 1 ----
  k_gemm64<float><<<2048, 256, 0, stream>>>(x, W1, bufA, n);
  k_aggregate<1><<<featBlocks, 256, 0, stream>>>(edges, rowStart, dinv, bufA, b1, bufB, n, 1);

  // ---- layer 2 ----
  k_gemm64<unsigned short><<<2048, 256, 0, stream>>>(bufB, W2, bufA, n);
  k_aggregate<0><<<featBlocks, 256, 0, stream>>>(edges, rowStart, dinv, bufA, b2, out, n, 0);
}

// Round 6
// 269.420 us; speedup vs baseline: 2.4907x; 1.1030x over previous
//
#include <hip/hip_runtime.h>

#define HID 64
#define NPB 256   // nodes per bucket (bucket = dst >> 8)

__device__ inline float bf2f(unsigned short u) {
  return __uint_as_float((unsigned int)u << 16);
}
__device__ inline unsigned short f2bf(float f) {
  unsigned int u = __float_as_uint(f);
  u += 0x7fff + ((u >> 16) & 1);  // round-to-nearest-even
  return (unsigned short)(u >> 16);
}

// ---- S1: per-block LDS histogram over buckets + padded-line global reservation ----
__global__ __launch_bounds__(256) void k_hist(const int* __restrict__ dst,
                                              unsigned int* __restrict__ bucketCnt,  // B*16 padded
                                              unsigned int* __restrict__ blockBase,  // [B][B]
                                              int B, int ept, int nE) {
  __shared__ unsigned int hist[512];
  for (int c = threadIdx.x; c < B; c += 256) hist[c] = 0;
  __syncthreads();
  int base = blockIdx.x * 256 * ept;
  for (int i = 0; i < ept; ++i) {
    int e = base + i * 256 + threadIdx.x;
    if (e < nE) atomicAdd(&hist[(unsigned)dst[e] >> 8], 1u);
  }
  __syncthreads();
  for (int c = threadIdx.x; c < B; c += 256) {
    unsigned int h = hist[c];
    unsigned int b = 0;
    if (h) b = atomicAdd(&bucketCnt[c * 16], h);  // 64B-padded: serial only per line
    blockBase[(size_t)blockIdx.x * B + c] = b;
  }
}

// ---- S2: exclusive scan of bucket totals (B <= 512) ----
__global__ __launch_bounds__(512) void k_bscan(const unsigned int* __restrict__ bucketCnt,
                                               int* __restrict__ bucketStart,
                                               int* __restrict__ rowStart,
                                               int B, int n, int nE) {
  __shared__ int s[512];
  int v = (threadIdx.x < (unsigned)B) ? (int)bucketCnt[threadIdx.x * 16] : 0;
  s[threadIdx.x] = v;
  __syncthreads();
  for (int o = 1; o < 512; o <<= 1) {
    int t = (threadIdx.x >= (unsigned)o) ? s[threadIdx.x - o] : 0;
    __syncthreads();
    s[threadIdx.x] += t;
    __syncthreads();
  }
  if (threadIdx.x < (unsigned)B) bucketStart[threadIdx.x] = s[threadIdx.x] - v;
  if (threadIdx.x == 0) { bucketStart[B] = nE; rowStart[n] = nE; }
}

// ---- S3: scatter edges into bucket regions via LDS cursors ----
// record: {src | dLoc<<24, ew_bits}  (src < 2^24)
__global__ __launch_bounds__(256) void k_bucket(const int* __restrict__ src,
                                                const int* __restrict__ dst,
                                                const float* __restrict__ ew,
                                                const int* __restrict__ bucketStart,
                                                const unsigned int* __restrict__ blockBase,
                                                int2* __restrict__ e8,
                                                int B, int ept, int nE) {
  __shared__ int cursor[512];
  for (int c = threadIdx.x; c < B; c += 256)
    cursor[c] = bucketStart[c] + (int)blockBase[(size_t)blockIdx.x * B + c];
  __syncthreads();
  int base = blockIdx.x * 256 * ept;
  for (int i = 0; i < ept; ++i) {
    int e = base + i * 256 + threadIdx.x;
    if (e < nE) {
      int d = dst[e];
      int slot = atomicAdd(&cursor[d >> 8], 1);
      e8[slot] = make_int2(src[e] | ((d & 255) << 24), __float_as_int(ew[e]));
    }
  }
}

// ---- S4a: per-bucket degrees via LDS float atomics; dinv coalesced ----
__global__ __launch_bounds__(NPB) void k_deg(const int2* __restrict__ e8,
                                             const int* __restrict__ bucketStart,
                                             float* __restrict__ dinv, int n) {
  __shared__ float deg[NPB];
  deg[threadIdx.x] = 1.0f;  // self-loop weight
  __syncthreads();
  int c = blockIdx.x;
  int i0 = bucketStart[c], i1 = bucketStart[c + 1];
  for (int i = i0 + threadIdx.x; i < i1; i += NPB) {
    int2 r = e8[i];
    atomicAdd(&deg[(unsigned)r.x >> 24], __int_as_float(r.y));
  }
  __syncthreads();
  int g = c * NPB + threadIdx.x;
  if (g < n) dinv[g] = rsqrtf(deg[threadIdx.x]);
}

// ---- S4b: per-bucket LDS counting sort -> rowStart + edges{src, norm} ----
__global__ __launch_bounds__(NPB) void k_sortfill(const int2* __restrict__ e8,
                                                  const int* __restrict__ bucketStart,
                                                  const float* __restrict__ dinv,
                                                  int* __restrict__ rowStart,
                                                  int2* __restrict__ edges, int n) {
  __shared__ int cnt[NPB];
  __shared__ int s[NPB];
  cnt[threadIdx.x] = 0;
  __syncthreads();
  int c = blockIdx.x;
  int i0 = bucketStart[c], i1 = bucketStart[c + 1];
  for (int i = i0 + threadIdx.x; i < i1; i += NPB)
    atomicAdd(&cnt[(unsigned)e8[i].x >> 24], 1);
  __syncthreads();
  int v = cnt[threadIdx.x];
  s[threadIdx.x] = v;
  __syncthreads();
  for (int o = 1; o < NPB; o <<= 1) {
    int t = (threadIdx.x >= (unsigned)o) ? s[threadIdx.x - o] : 0;
    __syncthreads();
    s[threadIdx.x] += t;
    __syncthreads();
  }
  int rowBase = i0 + s[threadIdx.x] - v;  // absolute exclusive start for my node
  int g = c * NPB + threadIdx.x;
  if (g < n) rowStart[g] = rowBase;
  __syncthreads();               // everyone done reading cnt/s
  cnt[threadIdx.x] = rowBase;    // reuse as cursor
  __syncthreads();
  for (int i = i0 + threadIdx.x; i < i1; i += NPB) {
    int2 r = e8[i];
    int l = (unsigned)r.x >> 24;
    int sn = r.x & 0xFFFFFF;
    int pos = atomicAdd(&cnt[l], 1);
    float norm = dinv[sn] * __int_as_float(r.y) * dinv[c * NPB + l];
    edges[pos] = make_int2(sn, __float_as_int(norm));
  }
}

// ---- dense 64x64 projection: lane j holds W column j; readlane-broadcast x ----
__device__ inline float readlane_f(float v, int l) {
  return __int_as_float(__builtin_amdgcn_readlane(__float_as_int(v), l));
}

template <typename TI>
__global__ __launch_bounds__(256) void k_gemm64(const TI* __restrict__ X,
                                                const float* __restrict__ W,
                                                unsigned short* __restrict__ Out, int n) {
  int lane = threadIdx.x & 63;
  float Wc[HID];
#pragma unroll
  for (int k = 0; k < HID; ++k) Wc[k] = W[k * HID + lane];
  int wave = (blockIdx.x * 256 + threadIdx.x) >> 6;
  int nwaves = (gridDim.x * 256) >> 6;
  for (int node = wave; node < n; node += nwaves) {
    TI raw = X[(size_t)node * HID + lane];
    float xl;
    if (sizeof(TI) == 2) xl = bf2f((unsigned short)raw);
    else xl = (float)raw;
    float a0 = 0.f, a1 = 0.f;
#pragma unroll
    for (int k = 0; k < HID; k += 2) {
      a0 = fmaf(readlane_f(xl, k), Wc[k], a0);
      a1 = fmaf(readlane_f(xl, k + 1), Wc[k + 1], a1);
    }
    Out[(size_t)node * HID + lane] = f2bf(a0 + a1);
  }
}

// ---- CSR aggregate: one wave per node, lane=channel; unroll-8 MLP; bf16 gathers ----
template <int OUT_BF16>
__global__ __launch_bounds__(256) void k_aggregate(const int2* __restrict__ edges,
                                                   const int* __restrict__ rowStart,
                                                   const float* __restrict__ dinv,
                                                   const unsigned short* __restrict__ Hin,
                                                   const float* __restrict__ bias,
                                                   void* __restrict__ outp, int n, int do_relu) {
  int j = threadIdx.x & 63;
  int node = __builtin_amdgcn_readfirstlane((blockIdx.x * 256 + threadIdx.x) >> 6);
  if (node >= n) return;
  int e0 = rowStart[node];
  int e1 = rowStart[node + 1];
  float di = dinv[node];
  float a0 = di * di * bf2f(Hin[(size_t)node * HID + j]);
  float a1 = 0.f, a2 = 0.f, a3 = 0.f, a4 = 0.f, a5 = 0.f, a6 = 0.f, a7 = 0.f;
  for (int e = e0; e < e1; e += 8) {
    int last = e1 - 1;
    int i1 = (e + 1 < e1) ? e + 1 : last;
    int i2 = (e + 2 < e1) ? e + 2 : last;
    int i3 = (e + 3 < e1) ? e + 3 : last;
    int i4 = (e + 4 < e1) ? e + 4 : last;
    int i5 = (e + 5 < e1) ? e + 5 : last;
    int i6 = (e + 6 < e1) ? e + 6 : last;
    int i7 = (e + 7 < e1) ? e + 7 : last;
    int2 r0 = edges[e];
    int2 r1 = edges[i1];
    int2 r2 = edges[i2];
    int2 r3 = edges[i3];
    int2 r4 = edges[i4];
    int2 r5 = edges[i5];
    int2 r6 = edges[i6];
    int2 r7 = edges[i7];
    float h0 = bf2f(Hin[(size_t)r0.x * HID + j]);
    float h1 = bf2f(Hin[(size_t)r1.x * HID + j]);
    float h2 = bf2f(Hin[(size_t)r2.x * HID + j]);
    float h3 = bf2f(Hin[(size_t)r3.x * HID + j]);
    float h4 = bf2f(Hin[(size_t)r4.x * HID + j]);
    float h5 = bf2f(Hin[(size_t)r5.x * HID + j]);
    float h6 = bf2f(Hin[(size_t)r6.x * HID + j]);
    float h7 = bf2f(Hin[(size_t)r7.x * HID + j]);
    float n0 = __int_as_float(r0.y);
    float n1 = (e + 1 < e1) ? __int_as_float(r1.y) : 0.f;
    float n2 = (e + 2 < e1) ? __int_as_float(r2.y) : 0.f;
    float n3 = (e + 3 < e1) ? __int_as_float(r3.y) : 0.f;
    float n4 = (e + 4 < e1) ? __int_as_float(r4.y) : 0.f;
    float n5 = (e + 5 < e1) ? __int_as_float(r5.y) : 0.f;
    float n6 = (e + 6 < e1) ? __int_as_float(r6.y) : 0.f;
    float n7 = (e + 7 < e1) ? __int_as_float(r7.y) : 0.f;
    a0 = fmaf(n0, h0, a0);
    a1 = fmaf(n1, h1, a1);
    a2 = fmaf(n2, h2, a2);
    a3 = fmaf(n3, h3, a3);
    a4 = fmaf(n4, h4, a4);
    a5 = fmaf(n5, h5, a5);
    a6 = fmaf(n6, h6, a6);
    a7 = fmaf(n7, h7, a7);
  }
  float acc = (((a0 + a1) + (a2 + a3)) + ((a4 + a5) + (a6 + a7))) + bias[j];
  if (do_relu) acc = fmaxf(acc, 0.f);
  if (OUT_BF16)
    ((unsigned short*)outp)[(size_t)node * HID + j] = f2bf(acc);
  else
    ((float*)outp)[(size_t)node * HID + j] = acc;
}

extern "C" void kernel_launch(void* const* d_in, const int* in_sizes, int n_in,
                              void* d_out, int out_size, void* d_ws, size_t ws_size,
                              hipStream_t stream) {
  const float* x  = (const float*)d_in[0];
  const int*   ei = (const int*)d_in[1];
  const float* ew = (const float*)d_in[2];
  const float* W1 = (const float*)d_in[3];
  const float* b1 = (const float*)d_in[4];
  const float* W2 = (const float*)d_in[5];
  const float* b2 = (const float*)d_in[6];
  float* out = (float*)d_out;

  const int n  = in_sizes[0] / HID;   // 100000
  const int nE = in_sizes[2];         // 1000000
  const int* src = ei;
  const int* dst = ei + nE;

  const int B   = (n + NPB - 1) / NPB;                // 391 buckets
  const int ept = (nE + B * 256 - 1) / (B * 256);     // edges per thread in S1/S3

  auto align512 = [](size_t v) { return (v + 511) & ~(size_t)511; };
  char* ws = (char*)d_ws;
  size_t off = 0;
  float* dinv        = (float*)(ws + off); off += align512((size_t)n * 4);
  int*   rowStart    = (int*)  (ws + off); off += align512((size_t)(n + 1) * 4);
  unsigned int* bucketCnt = (unsigned int*)(ws + off); off += align512((size_t)B * 16 * 4);
  int*   bucketStart = (int*)  (ws + off); off += align512((size_t)(B + 1) * 4);
  int2*  edges       = (int2*) (ws + off); off += align512((size_t)nE * 8);
  unsigned short* bufA = (unsigned short*)(ws + off); off += align512((size_t)n * HID * 2);
  unsigned short* bufB = (unsigned short*)(ws + off);

  // blockBase (B*B*4 ~ 612KB) + e8 (nE*8 = 8MB) alias onto bufA (12.8MB):
  // both dead before gemm1 writes bufA.
  unsigned int* blockBase = (unsigned int*)bufA;
  int2* e8 = (int2*)((char*)bufA + align512((size_t)B * B * 4));

  const int featBlocks = (n * HID + 255) / 256;

  // ---- CSR build: atomic-free counting sort by dst>>8 ----
  hipMemsetAsync(bucketCnt, 0, (size_t)B * 16 * 4, stream);
  k_hist<<<B, 256, 0, stream>>>(dst, bucketCnt, blockBase, B, ept, nE);
  k_bscan<<<1, 512, 0, stream>>>(bucketCnt, bucketStart, rowStart, B, n, nE);
  k_bucket<<<B, 256, 0, stream>>>(src, dst, ew, bucketStart, blockBase, e8, B, ept, nE);
  k_deg<<<B, NPB, 0, stream>>>(e8, bucketStart, dinv, n);
  k_sortfill<<<B, NPB, 0, stream>>>(e8, bucketStart, dinv, rowStart, edges, n);

  // ---- layer 1 ----
  k_gemm64<float><<<2048, 256, 0, stream>>>(x, W1, bufA, n);
  k_aggregate<1><<<featBlocks, 256, 0, stream>>>(edges, rowStart, dinv, bufA, b1, bufB, n, 1);

  // ---- layer 2 ----
  k_gemm64<unsigned short><<<2048, 256, 0, stream>>>(bufB, W2, bufA, n);
  k_aggregate<0><<<featBlocks, 256, 0, stream>>>(edges, rowStart, dinv, bufA, b2, out, n, 0);
}